// Round 1
// baseline (569.308 us; speedup 1.0000x reference)
//
#include <hip/hip_runtime.h>

#define LOG2E 1.44269504088896340736f

typedef __attribute__((ext_vector_type(8))) short bf16x8;
typedef __attribute__((ext_vector_type(4))) float f32x4;

__device__ __forceinline__ unsigned short f2b(float f) {
  union { float f; unsigned int u; } x; x.f = f;
  unsigned int u = x.u;
  return (unsigned short)((u + 0x7fffu + ((u >> 16) & 1u)) >> 16);
}

__device__ __forceinline__ void gld_lds16(const void* g, void* l) {
  __builtin_amdgcn_global_load_lds((const __attribute__((address_space(1))) void*)g,
                                   (__attribute__((address_space(3))) void*)l,
                                   16, 0, 0);
}

// ---------------- elementwise fp32 -> bf16 cast (x, y) ----------------
__global__ __launch_bounds__(256) void cast4(const float* __restrict__ in,
                                             unsigned short* __restrict__ out, int n4) {
  int i = blockIdx.x * 256 + threadIdx.x;
  if (i < n4) {
    float4 v = ((const float4*)in)[i];
    ushort4 o;
    o.x = f2b(v.x); o.y = f2b(v.y); o.z = f2b(v.z); o.w = f2b(v.w);
    ((ushort4*)out)[i] = o;
  }
}

// ---------------- transpose + cast: W (K x N) fp32 -> Wt (N x K) bf16 ----------------
__global__ __launch_bounds__(256) void transpose_cast(const float* __restrict__ W,
                                                      unsigned short* __restrict__ Wt,
                                                      int K, int N) {
  __shared__ float t[32][33];
  int j = threadIdx.x & 31, i0 = threadIdx.x >> 5;
  int nb = blockIdx.x * 32, kb = blockIdx.y * 32;
  #pragma unroll
  for (int p = 0; p < 4; ++p) {
    int i = i0 + p * 8;
    t[i][j] = W[(size_t)(kb + i) * N + nb + j];
  }
  __syncthreads();
  #pragma unroll
  for (int p = 0; p < 4; ++p) {
    int i = i0 + p * 8;
    Wt[(size_t)(nb + i) * K + kb + j] = f2b(t[j][i]);
  }
}

// ---------------- GEMM: C(MxN) = A(MxK) @ Bt(NxK)^T + bias ----------------
// A, Bt bf16 row-major (K contiguous). 128x128 tile, 4 waves of 64x64,
// 16x16x32 bf16 MFMA, global_load_lds width-16 staging (m97 structure).
template <int OUT_BF16>
__global__ __launch_bounds__(256)
void gemm_bt(const unsigned short* __restrict__ A,
             const unsigned short* __restrict__ Bt,
             const float* __restrict__ bias,
             void* __restrict__ Cout, int M, int N, int K) {
  __shared__ __align__(16) unsigned short As[128 * 64];
  __shared__ __align__(16) unsigned short Bs[128 * 64];
  const int tid = threadIdx.x;
  const int bn = blockIdx.x, bm = blockIdx.y;
  const int wave = tid >> 6, lane = tid & 63;
  const int wm = (wave >> 1) * 64, wn = (wave & 1) * 64;
  const int lrow = lane & 15, lk = (lane >> 4) * 8;
  const int quad = lane >> 4;

  f32x4 acc[4][4];
  #pragma unroll
  for (int i = 0; i < 4; ++i)
    #pragma unroll
    for (int j = 0; j < 4; ++j)
      #pragma unroll
      for (int r = 0; r < 4; ++r) acc[i][j][r] = 0.f;

  const unsigned short* Ab = A + (size_t)(bm * 128) * K;
  const unsigned short* Bb = Bt + (size_t)(bn * 128) * K;

  for (int k0 = 0; k0 < K; k0 += 64) {
    #pragma unroll
    for (int i = 0; i < 4; ++i) {
      int e = i * 256 + tid;
      int row = e >> 3, c16 = e & 7;
      gld_lds16(Ab + (size_t)row * K + k0 + c16 * 8, &As[e * 8]);
    }
    #pragma unroll
    for (int i = 0; i < 4; ++i) {
      int e = i * 256 + tid;
      int row = e >> 3, c16 = e & 7;
      gld_lds16(Bb + (size_t)row * K + k0 + c16 * 8, &Bs[e * 8]);
    }
    __builtin_amdgcn_s_waitcnt(0);
    __syncthreads();
    #pragma unroll
    for (int ks = 0; ks < 2; ++ks) {
      bf16x8 af[4], bf[4];
      #pragma unroll
      for (int i = 0; i < 4; ++i)
        af[i] = *(const bf16x8*)&As[(wm + i * 16 + lrow) * 64 + ks * 32 + lk];
      #pragma unroll
      for (int j = 0; j < 4; ++j)
        bf[j] = *(const bf16x8*)&Bs[(wn + j * 16 + lrow) * 64 + ks * 32 + lk];
      #pragma unroll
      for (int i = 0; i < 4; ++i)
        #pragma unroll
        for (int j = 0; j < 4; ++j)
          acc[i][j] = __builtin_amdgcn_mfma_f32_16x16x32_bf16(af[i], bf[j], acc[i][j], 0, 0, 0);
    }
    __syncthreads();
  }

  #pragma unroll
  for (int i = 0; i < 4; ++i) {
    const int row0 = bm * 128 + wm + i * 16 + quad * 4;
    #pragma unroll
    for (int j = 0; j < 4; ++j) {
      const int col = bn * 128 + wn + j * 16 + lrow;
      const float bv = bias[col];
      #pragma unroll
      for (int r = 0; r < 4; ++r) {
        float v = acc[i][j][r] + bv;
        size_t off = (size_t)(row0 + r) * N + col;
        if (OUT_BF16) ((unsigned short*)Cout)[off] = f2b(v);
        else ((float*)Cout)[off] = v;
      }
    }
  }
}

// ---------------- flash attention ----------------
// grid (S/128, H, B); 256 threads = 4 waves, each wave owns 32 q-rows.
// S-tile = 64 keys. Q frags in registers; K row-major, V transposed in LDS
// (pitch 72 shorts = 144B, 16B-aligned rows, ~2-way bank conflicts).
__global__ __launch_bounds__(256)
void attn(const unsigned short* __restrict__ qm,
          const unsigned short* __restrict__ kv,
          const float* __restrict__ mask,
          unsigned short* __restrict__ vals) {
  const int qt = blockIdx.x, h = blockIdx.y, b = blockIdx.z;
  const int tid = threadIdx.x, lane = tid & 63, w = tid >> 6;
  const int lrow = lane & 15, quad = lane >> 4;

  __shared__ __align__(16) unsigned short Ks[64 * 72];
  __shared__ __align__(16) unsigned short Vs[64 * 72];   // Vt[d][key]
  __shared__ __align__(16) unsigned short Ps[128 * 72];  // P tile; also Q staging

  // stage Q (128 x 64) into Ps
  {
    const unsigned short* qb = qm + (size_t)(b * 2048 + qt * 128) * 1024 + h * 64;
    #pragma unroll
    for (int c0 = 0; c0 < 1024; c0 += 256) {
      int c = c0 + tid;
      int row = c >> 3, ch = c & 7;
      *(uint4*)&Ps[row * 72 + ch * 8] = *(const uint4*)(qb + (size_t)row * 1024 + ch * 8);
    }
  }
  __syncthreads();
  bf16x8 qf[2][2];
  #pragma unroll
  for (int im = 0; im < 2; ++im)
    #pragma unroll
    for (int ks = 0; ks < 2; ++ks)
      qf[im][ks] = *(const bf16x8*)&Ps[(w * 32 + im * 16 + lrow) * 72 + ks * 32 + quad * 8];
  __syncthreads();

  f32x4 o_acc[2][4];
  float m_i[2][4], l_i[2][4];
  #pragma unroll
  for (int im = 0; im < 2; ++im)
    #pragma unroll
    for (int r = 0; r < 4; ++r) { m_i[im][r] = -1e30f; l_i[im][r] = 0.f; }
  #pragma unroll
  for (int im = 0; im < 2; ++im)
    #pragma unroll
    for (int jn = 0; jn < 4; ++jn)
      #pragma unroll
      for (int r = 0; r < 4; ++r) o_acc[im][jn][r] = 0.f;

  const unsigned short* kvb = kv + (size_t)(b * 2048) * 2048 + h * 128;
  const float* mb = mask + (size_t)(qt * 128 + w * 32) * 2048;

  for (int kt = 0; kt < 32; ++kt) {
    __syncthreads();
    // stage K rows + V transposed
    #pragma unroll
    for (int c0 = 0; c0 < 512; c0 += 256) {
      int c = c0 + tid;
      int row = c >> 3, ch = c & 7;
      const unsigned short* src = kvb + (size_t)(kt * 64 + row) * 2048 + ch * 8;
      *(uint4*)&Ks[row * 72 + ch * 8] = *(const uint4*)src;
      unsigned short tmp[8];
      *(uint4*)tmp = *(const uint4*)(src + 64);
      #pragma unroll
      for (int j = 0; j < 8; ++j) Vs[(ch * 8 + j) * 72 + row] = tmp[j];
    }
    __syncthreads();

    // S = Q @ K^T
    f32x4 z[2][4];
    #pragma unroll
    for (int im = 0; im < 2; ++im)
      #pragma unroll
      for (int jn = 0; jn < 4; ++jn)
        #pragma unroll
        for (int r = 0; r < 4; ++r) z[im][jn][r] = 0.f;
    #pragma unroll
    for (int ks = 0; ks < 2; ++ks) {
      bf16x8 kf[4];
      #pragma unroll
      for (int jn = 0; jn < 4; ++jn)
        kf[jn] = *(const bf16x8*)&Ks[(jn * 16 + lrow) * 72 + ks * 32 + quad * 8];
      #pragma unroll
      for (int im = 0; im < 2; ++im)
        #pragma unroll
        for (int jn = 0; jn < 4; ++jn)
          z[im][jn] = __builtin_amdgcn_mfma_f32_16x16x32_bf16(qf[im][ks], kf[jn], z[im][jn], 0, 0, 0);
    }

    // scale + mask
    #pragma unroll
    for (int im = 0; im < 2; ++im)
      #pragma unroll
      for (int jn = 0; jn < 4; ++jn)
        #pragma unroll
        for (int r = 0; r < 4; ++r)
          z[im][jn][r] = z[im][jn][r] * 0.125f +
              mb[(size_t)(im * 16 + quad * 4 + r) * 2048 + kt * 64 + jn * 16 + lrow];

    // online softmax (rows live in 16-lane groups)
    #pragma unroll
    for (int im = 0; im < 2; ++im)
      #pragma unroll
      for (int r = 0; r < 4; ++r) {
        float v = z[im][0][r];
        v = fmaxf(v, z[im][1][r]); v = fmaxf(v, z[im][2][r]); v = fmaxf(v, z[im][3][r]);
        v = fmaxf(v, __shfl_xor(v, 1));
        v = fmaxf(v, __shfl_xor(v, 2));
        v = fmaxf(v, __shfl_xor(v, 4));
        v = fmaxf(v, __shfl_xor(v, 8));
        float mn = fmaxf(m_i[im][r], v);
        float alpha = exp2f((m_i[im][r] - mn) * LOG2E);
        m_i[im][r] = mn;
        #pragma unroll
        for (int jn = 0; jn < 4; ++jn)
          z[im][jn][r] = exp2f((z[im][jn][r] - mn) * LOG2E);
        float s = z[im][0][r] + z[im][1][r] + z[im][2][r] + z[im][3][r];
        s += __shfl_xor(s, 1);
        s += __shfl_xor(s, 2);
        s += __shfl_xor(s, 4);
        s += __shfl_xor(s, 8);
        l_i[im][r] = l_i[im][r] * alpha + s;
        #pragma unroll
        for (int jn = 0; jn < 4; ++jn)
          o_acc[im][jn][r] *= alpha;
      }

    // P -> LDS (C-layout -> A-layout round trip), wave-private rows
    #pragma unroll
    for (int im = 0; im < 2; ++im)
      #pragma unroll
      for (int jn = 0; jn < 4; ++jn)
        #pragma unroll
        for (int r = 0; r < 4; ++r)
          Ps[(w * 32 + im * 16 + quad * 4 + r) * 72 + jn * 16 + lrow] = f2b(z[im][jn][r]);
    __builtin_amdgcn_s_waitcnt(0xC07F);  // lgkmcnt(0): our writes visible to our reads

    // O += P @ V
    #pragma unroll
    for (int ks = 0; ks < 2; ++ks) {
      bf16x8 pf[2], vf[4];
      #pragma unroll
      for (int im = 0; im < 2; ++im)
        pf[im] = *(const bf16x8*)&Ps[(w * 32 + im * 16 + lrow) * 72 + ks * 32 + quad * 8];
      #pragma unroll
      for (int jn = 0; jn < 4; ++jn)
        vf[jn] = *(const bf16x8*)&Vs[(jn * 16 + lrow) * 72 + ks * 32 + quad * 8];
      #pragma unroll
      for (int im = 0; im < 2; ++im)
        #pragma unroll
        for (int jn = 0; jn < 4; ++jn)
          o_acc[im][jn] = __builtin_amdgcn_mfma_f32_16x16x32_bf16(pf[im], vf[jn], o_acc[im][jn], 0, 0, 0);
    }
  }

  unsigned short* ob = vals + (size_t)(b * 2048 + qt * 128 + w * 32) * 1024 + h * 64;
  #pragma unroll
  for (int im = 0; im < 2; ++im)
    #pragma unroll
    for (int r = 0; r < 4; ++r) {
      float inv = 1.f / l_i[im][r];
      #pragma unroll
      for (int jn = 0; jn < 4; ++jn)
        ob[(size_t)(im * 16 + quad * 4 + r) * 1024 + jn * 16 + lrow] =
            f2b(o_acc[im][jn][r] * inv);
    }
}

extern "C" void kernel_launch(void* const* d_in, const int* in_sizes, int n_in,
                              void* d_out, int out_size, void* d_ws, size_t ws_size,
                              hipStream_t stream) {
  const float* x    = (const float*)d_in[0];
  const float* y    = (const float*)d_in[1];
  const float* mask = (const float*)d_in[2];
  const float* Wkv  = (const float*)d_in[3];
  const float* bkv  = (const float*)d_in[4];
  const float* Wq   = (const float*)d_in[5];
  const float* bq   = (const float*)d_in[6];
  const float* Wo   = (const float*)d_in[7];
  const float* bo   = (const float*)d_in[8];

  char* ws = (char*)d_ws;
  unsigned short* xb    = (unsigned short*)(ws + ((size_t)0 << 20));
  unsigned short* yb    = (unsigned short*)(ws + ((size_t)16 << 20));
  unsigned short* wkvt  = (unsigned short*)(ws + ((size_t)32 << 20));
  unsigned short* wqt   = (unsigned short*)(ws + ((size_t)36 << 20));
  unsigned short* wot   = (unsigned short*)(ws + ((size_t)38 << 20));
  unsigned short* kvb   = (unsigned short*)(ws + ((size_t)40 << 20));
  unsigned short* qb    = (unsigned short*)(ws + ((size_t)72 << 20));
  unsigned short* valsb = (unsigned short*)(ws + ((size_t)88 << 20));

  // casts
  cast4<<<8192, 256, 0, stream>>>(x, xb, 2097152);
  cast4<<<8192, 256, 0, stream>>>(y, yb, 2097152);
  transpose_cast<<<dim3(64, 32), 256, 0, stream>>>(Wkv, wkvt, 1024, 2048);
  transpose_cast<<<dim3(32, 32), 256, 0, stream>>>(Wq, wqt, 1024, 1024);
  transpose_cast<<<dim3(32, 32), 256, 0, stream>>>(Wo, wot, 1024, 1024);

  // kv = x @ Wkv + bkv   (8192 x 2048)
  gemm_bt<1><<<dim3(16, 64), 256, 0, stream>>>(xb, wkvt, bkv, kvb, 8192, 2048, 1024);
  // q = y @ Wq + bq      (8192 x 1024)
  gemm_bt<1><<<dim3(8, 64), 256, 0, stream>>>(yb, wqt, bq, qb, 8192, 1024, 1024);
  // attention
  attn<<<dim3(16, 16, 4), 256, 0, stream>>>(qb, kvb, mask, valsb);
  // out = vals @ Wo + bo (8192 x 1024, fp32)
  gemm_bt<0><<<dim3(8, 64), 256, 0, stream>>>(valsb, wot, bo, (float*)d_out, 8192, 1024, 1024);
}

// Round 2
// 480.033 us; speedup vs baseline: 1.1860x; 1.1860x over previous
//
#include <hip/hip_runtime.h>

#define LOG2E 1.44269504088896340736f

typedef __attribute__((ext_vector_type(8))) short bf16x8;
typedef __attribute__((ext_vector_type(4))) float f32x4;

__device__ __forceinline__ unsigned short f2b(float f) {
  union { float f; unsigned int u; } x; x.f = f;
  return (unsigned short)((x.u + 0x8000u) >> 16);
}

// pack two fp32 -> two bf16 (round-to-nearest, ties up) in 3 VALU ops
__device__ __forceinline__ unsigned int pk_bf16(float a, float b) {
  union { float f; unsigned int u; } xa, xb; xa.f = a; xb.f = b;
  return __builtin_amdgcn_perm(xb.u + 0x8000u, xa.u + 0x8000u, 0x07060302);
}

__device__ __forceinline__ void gld_lds16(const void* g, void* l) {
  __builtin_amdgcn_global_load_lds((const __attribute__((address_space(1))) void*)g,
                                   (__attribute__((address_space(3))) void*)l,
                                   16, 0, 0);
}

// ---------------- elementwise fp32 -> bf16 cast (x, y) ----------------
__global__ __launch_bounds__(256) void cast4(const float* __restrict__ in,
                                             unsigned short* __restrict__ out, int n4) {
  int i = blockIdx.x * 256 + threadIdx.x;
  if (i < n4) {
    float4 v = ((const float4*)in)[i];
    uint2 o;
    o.x = pk_bf16(v.x, v.y);
    o.y = pk_bf16(v.z, v.w);
    ((uint2*)out)[i] = o;
  }
}

// ---------------- transpose + cast: W (K x N) fp32 -> Wt (N x K) bf16 ----------------
__global__ __launch_bounds__(256) void transpose_cast(const float* __restrict__ W,
                                                      unsigned short* __restrict__ Wt,
                                                      int K, int N) {
  __shared__ float t[32][33];
  int j = threadIdx.x & 31, i0 = threadIdx.x >> 5;
  int nb = blockIdx.x * 32, kb = blockIdx.y * 32;
  #pragma unroll
  for (int p = 0; p < 4; ++p) {
    int i = i0 + p * 8;
    t[i][j] = W[(size_t)(kb + i) * N + nb + j];
  }
  __syncthreads();
  #pragma unroll
  for (int p = 0; p < 4; ++p) {
    int i = i0 + p * 8;
    Wt[(size_t)(nb + i) * K + kb + j] = f2b(t[j][i]);
  }
}

// ---------------- GEMM: C(MxN) = A(MxK) @ Bt(NxK)^T + bias ----------------
// MODE 0: fp32 C out. MODE 1: kv -> K[b,h,s,64] + Vt[b,h,64,s]. MODE 2: q -> Q[b,h,s,64].
template <int MODE>
__global__ __launch_bounds__(256)
void gemm128(const unsigned short* __restrict__ A,
             const unsigned short* __restrict__ Bt,
             const float* __restrict__ bias,
             void* __restrict__ out0, void* __restrict__ out1,
             int M, int N, int K) {
  __shared__ __align__(16) unsigned short As[128 * 64];
  __shared__ __align__(16) unsigned short Bs[128 * 64];
  const int tid = threadIdx.x;
  const int bn = blockIdx.x, bm = blockIdx.y;
  const int wave = tid >> 6, lane = tid & 63;
  const int wm = (wave >> 1) * 64, wn = (wave & 1) * 64;
  const int lrow = lane & 15, lk = (lane >> 4) * 8;
  const int quad = lane >> 4;

  f32x4 acc[4][4];
  #pragma unroll
  for (int i = 0; i < 4; ++i)
    #pragma unroll
    for (int j = 0; j < 4; ++j)
      #pragma unroll
      for (int r = 0; r < 4; ++r) acc[i][j][r] = 0.f;

  const unsigned short* Ab = A + (size_t)(bm * 128) * K;
  const unsigned short* Bb = Bt + (size_t)(bn * 128) * K;

  for (int k0 = 0; k0 < K; k0 += 64) {
    #pragma unroll
    for (int i = 0; i < 4; ++i) {
      int e = i * 256 + tid;
      int row = e >> 3, c16 = e & 7;
      gld_lds16(Ab + (size_t)row * K + k0 + c16 * 8, &As[e * 8]);
    }
    #pragma unroll
    for (int i = 0; i < 4; ++i) {
      int e = i * 256 + tid;
      int row = e >> 3, c16 = e & 7;
      gld_lds16(Bb + (size_t)row * K + k0 + c16 * 8, &Bs[e * 8]);
    }
    __builtin_amdgcn_s_waitcnt(0);
    __syncthreads();
    #pragma unroll
    for (int ks = 0; ks < 2; ++ks) {
      bf16x8 af[4], bf[4];
      #pragma unroll
      for (int i = 0; i < 4; ++i)
        af[i] = *(const bf16x8*)&As[(wm + i * 16 + lrow) * 64 + ks * 32 + lk];
      #pragma unroll
      for (int j = 0; j < 4; ++j)
        bf[j] = *(const bf16x8*)&Bs[(wn + j * 16 + lrow) * 64 + ks * 32 + lk];
      #pragma unroll
      for (int i = 0; i < 4; ++i)
        #pragma unroll
        for (int j = 0; j < 4; ++j)
          acc[i][j] = __builtin_amdgcn_mfma_f32_16x16x32_bf16(af[i], bf[j], acc[i][j], 0, 0, 0);
    }
    __syncthreads();
  }

  const int col0 = bn * 128 + wn;  // wave-uniform 64-col range
  #pragma unroll
  for (int i = 0; i < 4; ++i) {
    const int row0 = bm * 128 + wm + i * 16 + quad * 4;  // 4 consecutive rows
    const int b = row0 >> 11, s0 = row0 & 2047;
    #pragma unroll
    for (int j = 0; j < 4; ++j) {
      const int cc = j * 16 + lrow;          // 0..63 within wave range
      const float bv = bias[col0 + cc];
      float v0 = acc[i][j][0] + bv, v1 = acc[i][j][1] + bv;
      float v2 = acc[i][j][2] + bv, v3 = acc[i][j][3] + bv;
      if (MODE == 0) {
        float* C = (float*)out0;
        size_t off = (size_t)row0 * N + col0 + cc;
        C[off] = v0; C[off + N] = v1; C[off + 2 * N] = v2; C[off + 3 * N] = v3;
      } else if (MODE == 1) {
        const int h = col0 >> 7;
        if ((col0 & 64) == 0) {  // K half: K[b,h,s,64]
          unsigned short* Kb = (unsigned short*)out0;
          size_t base = ((size_t)(b * 16 + h) * 2048 + s0) * 64 + cc;
          Kb[base] = f2b(v0); Kb[base + 64] = f2b(v1);
          Kb[base + 128] = f2b(v2); Kb[base + 192] = f2b(v3);
        } else {                 // V half: Vt[b,h,64,s]
          unsigned short* Vt = (unsigned short*)out1;
          size_t base = ((size_t)(b * 16 + h) * 64 + cc) * 2048 + s0;
          uint2 p; p.x = pk_bf16(v0, v1); p.y = pk_bf16(v2, v3);
          *(uint2*)&Vt[base] = p;
        }
      } else {  // MODE 2: Q[b,h,s,64]
        const int h = col0 >> 6;
        unsigned short* Qb = (unsigned short*)out0;
        size_t base = ((size_t)(b * 16 + h) * 2048 + s0) * 64 + cc;
        Qb[base] = f2b(v0); Qb[base + 64] = f2b(v1);
        Qb[base + 128] = f2b(v2); Qb[base + 192] = f2b(v3);
      }
    }
  }
}

// ---------------- flash attention (transposed: S^T = K Q^T, O^T = V^T P^T) ----
// grid (S/128, H, B); 4 waves, each owns 32 q (columns of S^T).
__global__ __launch_bounds__(256)
void attn(const unsigned short* __restrict__ Qbuf,
          const unsigned short* __restrict__ Kbuf,
          const unsigned short* __restrict__ Vtbuf,
          const float* __restrict__ mask,
          unsigned short* __restrict__ vals) {
  const int qt = blockIdx.x, h = blockIdx.y, b = blockIdx.z;
  const int tid = threadIdx.x, lane = tid & 63, w = tid >> 6;
  const int lrow = lane & 15, quad = lane >> 4;

  __shared__ __align__(16) unsigned short Ks[64 * 64];   // K tile  [key][d]
  __shared__ __align__(16) unsigned short Vs[64 * 64];   // V^T tile[d][key]
  __shared__ __align__(16) unsigned short Ps[128 * 72];  // P^T as [q][key] (pitch 72); Q staging (pitch 64)

  // stage Q (128 x 64) into Ps region, pitch 64
  const unsigned short* qb = Qbuf + ((size_t)(b * 16 + h) * 2048 + qt * 128) * 64;
  #pragma unroll
  for (int i = 0; i < 4; ++i) {
    int e = i * 256 + tid;
    gld_lds16(qb + (size_t)e * 8, &Ps[e * 8]);
  }
  __builtin_amdgcn_s_waitcnt(0);
  __syncthreads();
  bf16x8 qf[2][2];  // [iq][ks]  B-operand: n=q, k=d
  #pragma unroll
  for (int iq = 0; iq < 2; ++iq)
    #pragma unroll
    for (int ks = 0; ks < 2; ++ks)
      qf[iq][ks] = *(const bf16x8*)&Ps[(w * 32 + iq * 16 + lrow) * 64 + ks * 32 + quad * 8];

  f32x4 o_acc[4][2];  // [id][iq]: O^T, d=id*16+quad*4+r, q=iq*16+lrow
  float m_i[2] = {-1e30f, -1e30f}, l_i[2] = {0.f, 0.f};
  #pragma unroll
  for (int id = 0; id < 4; ++id)
    #pragma unroll
    for (int iq = 0; iq < 2; ++iq)
      #pragma unroll
      for (int r = 0; r < 4; ++r) o_acc[id][iq][r] = 0.f;

  const unsigned short* kb  = Kbuf  + (size_t)(b * 16 + h) * 2048 * 64;
  const unsigned short* vtb = Vtbuf + (size_t)(b * 16 + h) * 64 * 2048;
  const float* mb = mask + (size_t)(qt * 128 + w * 32) * 2048;

  for (int kt = 0; kt < 32; ++kt) {
    __syncthreads();
    #pragma unroll
    for (int i = 0; i < 2; ++i) {  // K tile: fully contiguous 8 KB
      int e = i * 256 + tid;
      gld_lds16(kb + (size_t)kt * 4096 + e * 8, &Ks[e * 8]);
    }
    #pragma unroll
    for (int i = 0; i < 2; ++i) {  // V^T tile: 64 rows of 128 B
      int e = i * 256 + tid;
      int row = e >> 3, ch = e & 7;
      gld_lds16(vtb + (size_t)row * 2048 + kt * 64 + ch * 8, &Vs[e * 8]);
    }
    __builtin_amdgcn_s_waitcnt(0);
    __syncthreads();

    // S^T tiles: z[ik][iq], key = ik*16+quad*4+r, q = iq*16+lrow
    f32x4 z[4][2];
    #pragma unroll
    for (int ik = 0; ik < 4; ++ik)
      #pragma unroll
      for (int iq = 0; iq < 2; ++iq)
        #pragma unroll
        for (int r = 0; r < 4; ++r) z[ik][iq][r] = 0.f;
    #pragma unroll
    for (int ks = 0; ks < 2; ++ks) {
      bf16x8 kf[4];  // A-operand: m=key, k=d
      #pragma unroll
      for (int ik = 0; ik < 4; ++ik)
        kf[ik] = *(const bf16x8*)&Ks[(ik * 16 + lrow) * 64 + ks * 32 + quad * 8];
      #pragma unroll
      for (int ik = 0; ik < 4; ++ik)
        #pragma unroll
        for (int iq = 0; iq < 2; ++iq)
          z[ik][iq] = __builtin_amdgcn_mfma_f32_16x16x32_bf16(kf[ik], qf[iq][ks], z[ik][iq], 0, 0, 0);
    }

    // scale + mask (float4 loads along key dim)
    #pragma unroll
    for (int ik = 0; ik < 4; ++ik)
      #pragma unroll
      for (int iq = 0; iq < 2; ++iq) {
        float4 mv = *(const float4*)&mb[(size_t)(iq * 16 + lrow) * 2048 + kt * 64 + ik * 16 + quad * 4];
        z[ik][iq][0] = fmaf(z[ik][iq][0], 0.125f, mv.x);
        z[ik][iq][1] = fmaf(z[ik][iq][1], 0.125f, mv.y);
        z[ik][iq][2] = fmaf(z[ik][iq][2], 0.125f, mv.z);
        z[ik][iq][3] = fmaf(z[ik][iq][3], 0.125f, mv.w);
      }

    // online softmax per q (= per iq, per lrow): 16 in-lane + 2 shuffles
    float alpha[2];
    #pragma unroll
    for (int iq = 0; iq < 2; ++iq) {
      float a0 = fmaxf(fmaxf(z[0][iq][0], z[0][iq][1]), fmaxf(z[0][iq][2], z[0][iq][3]));
      float a1 = fmaxf(fmaxf(z[1][iq][0], z[1][iq][1]), fmaxf(z[1][iq][2], z[1][iq][3]));
      float a2 = fmaxf(fmaxf(z[2][iq][0], z[2][iq][1]), fmaxf(z[2][iq][2], z[2][iq][3]));
      float a3 = fmaxf(fmaxf(z[3][iq][0], z[3][iq][1]), fmaxf(z[3][iq][2], z[3][iq][3]));
      float mx = fmaxf(fmaxf(a0, a1), fmaxf(a2, a3));
      mx = fmaxf(mx, __shfl_xor(mx, 16));
      mx = fmaxf(mx, __shfl_xor(mx, 32));
      float mn = fmaxf(m_i[iq], mx);
      alpha[iq] = exp2f((m_i[iq] - mn) * LOG2E);
      m_i[iq] = mn;
      float nt = mn * LOG2E;
      float s0 = 0.f, s1 = 0.f;
      #pragma unroll
      for (int ik = 0; ik < 4; ++ik) {
        #pragma unroll
        for (int r = 0; r < 4; ++r)
          z[ik][iq][r] = exp2f(fmaf(z[ik][iq][r], LOG2E, -nt));
        s0 += z[ik][iq][0] + z[ik][iq][1];
        s1 += z[ik][iq][2] + z[ik][iq][3];
      }
      float s = s0 + s1;
      s += __shfl_xor(s, 16);
      s += __shfl_xor(s, 32);
      l_i[iq] = l_i[iq] * alpha[iq] + s;
    }

    // P^T -> LDS as [q][key], packed b64 writes (4 consecutive keys)
    #pragma unroll
    for (int ik = 0; ik < 4; ++ik)
      #pragma unroll
      for (int iq = 0; iq < 2; ++iq) {
        uint2 p;
        p.x = pk_bf16(z[ik][iq][0], z[ik][iq][1]);
        p.y = pk_bf16(z[ik][iq][2], z[ik][iq][3]);
        *(uint2*)&Ps[(w * 32 + iq * 16 + lrow) * 72 + ik * 16 + quad * 4] = p;
      }

    // rescale O
    #pragma unroll
    for (int id = 0; id < 4; ++id)
      #pragma unroll
      for (int iq = 0; iq < 2; ++iq)
        #pragma unroll
        for (int r = 0; r < 4; ++r) o_acc[id][iq][r] *= alpha[iq];

    __builtin_amdgcn_s_waitcnt(0xC07F);  // lgkmcnt(0): our Ps writes -> our reads

    // O^T += V^T P^T
    #pragma unroll
    for (int ks = 0; ks < 2; ++ks) {
      bf16x8 vf[4], pf[2];
      #pragma unroll
      for (int id = 0; id < 4; ++id)
        vf[id] = *(const bf16x8*)&Vs[(id * 16 + lrow) * 64 + ks * 32 + quad * 8];
      #pragma unroll
      for (int iq = 0; iq < 2; ++iq)
        pf[iq] = *(const bf16x8*)&Ps[(w * 32 + iq * 16 + lrow) * 72 + ks * 32 + quad * 8];
      #pragma unroll
      for (int id = 0; id < 4; ++id)
        #pragma unroll
        for (int iq = 0; iq < 2; ++iq)
          o_acc[id][iq] = __builtin_amdgcn_mfma_f32_16x16x32_bf16(vf[id], pf[iq], o_acc[id][iq], 0, 0, 0);
    }
  }

  // epilogue: O^T -> vals[b][q][h*64+d], packed 8B stores (4 consecutive d)
  unsigned short* ob = vals + (size_t)(b * 2048 + qt * 128 + w * 32) * 1024 + h * 64;
  #pragma unroll
  for (int iq = 0; iq < 2; ++iq) {
    float inv = 1.f / l_i[iq];
    #pragma unroll
    for (int id = 0; id < 4; ++id) {
      uint2 p;
      p.x = pk_bf16(o_acc[id][iq][0] * inv, o_acc[id][iq][1] * inv);
      p.y = pk_bf16(o_acc[id][iq][2] * inv, o_acc[id][iq][3] * inv);
      *(uint2*)&ob[(size_t)(iq * 16 + lrow) * 1024 + id * 16 + quad * 4] = p;
    }
  }
}

extern "C" void kernel_launch(void* const* d_in, const int* in_sizes, int n_in,
                              void* d_out, int out_size, void* d_ws, size_t ws_size,
                              hipStream_t stream) {
  const float* x    = (const float*)d_in[0];
  const float* y    = (const float*)d_in[1];
  const float* mask = (const float*)d_in[2];
  const float* Wkv  = (const float*)d_in[3];
  const float* bkv  = (const float*)d_in[4];
  const float* Wq   = (const float*)d_in[5];
  const float* bq   = (const float*)d_in[6];
  const float* Wo   = (const float*)d_in[7];
  const float* bo   = (const float*)d_in[8];

  char* ws = (char*)d_ws;
  unsigned short* xb    = (unsigned short*)(ws + ((size_t)0 << 20));
  unsigned short* yb    = (unsigned short*)(ws + ((size_t)16 << 20));
  unsigned short* wkvt  = (unsigned short*)(ws + ((size_t)32 << 20));
  unsigned short* wqt   = (unsigned short*)(ws + ((size_t)36 << 20));
  unsigned short* wot   = (unsigned short*)(ws + ((size_t)38 << 20));
  unsigned short* kbuf  = (unsigned short*)(ws + ((size_t)40 << 20));
  unsigned short* vtbuf = (unsigned short*)(ws + ((size_t)56 << 20));
  unsigned short* qbuf  = (unsigned short*)(ws + ((size_t)72 << 20));
  unsigned short* valsb = (unsigned short*)(ws + ((size_t)88 << 20));

  cast4<<<8192, 256, 0, stream>>>(x, xb, 2097152);
  cast4<<<8192, 256, 0, stream>>>(y, yb, 2097152);
  transpose_cast<<<dim3(64, 32), 256, 0, stream>>>(Wkv, wkvt, 1024, 2048);
  transpose_cast<<<dim3(32, 32), 256, 0, stream>>>(Wq, wqt, 1024, 1024);
  transpose_cast<<<dim3(32, 32), 256, 0, stream>>>(Wo, wot, 1024, 1024);

  // kv = x @ Wkv + bkv -> K[b,h,s,64], Vt[b,h,64,s]
  gemm128<1><<<dim3(16, 64), 256, 0, stream>>>(xb, wkvt, bkv, kbuf, vtbuf, 8192, 2048, 1024);
  // q = y @ Wq + bq -> Q[b,h,s,64]
  gemm128<2><<<dim3(8, 64), 256, 0, stream>>>(yb, wqt, bq, qbuf, nullptr, 8192, 1024, 1024);
  // attention -> vals [b,s,1024] bf16
  attn<<<dim3(16, 16, 4), 256, 0, stream>>>(qbuf, kbuf, vtbuf, mask, valsb);
  // out = vals @ Wo + bo (fp32)
  gemm128<0><<<dim3(8, 64), 256, 0, stream>>>(valsb, wot, bo, (float*)d_out, nullptr, 8192, 1024, 1024);
}